// Round 2
// baseline (974.635 us; speedup 1.0000x reference)
//
#include <hip/hip_runtime.h>
#include <stdint.h>

// Problem: B=64, DIM=512, T=2048, S=1024.
// out[b][s][t] = softmax_s( 2*cross - msq[s] ),  cross = sum_d units[d][s]*H[b][d][t].
// Pipeline:
//   k_prep_units: units fp32 -> U^T bf16 hi/lo [s][d] in ws, + msq[s].
//   k_prep_h:     H fp32 [b][d][t] -> H^T bf16 hi/lo [b][t][d] in ws (LDS transpose).
//   k_gemm:       G[s][t] = U^T * H_b via 3x bf16 MFMA (hi/lo split), raw logits -> d_out.
//                 256x128 tile, BK=32 slabs, 3-slot LDS ring, counted vmcnt (T3+T4),
//                 setprio (T5), bijective XCD swizzle (T1), src-addr XOR swizzle (T2-equiv).
//   k_softmax:    in-place softmax over s (16 t-columns per block, logits held in regs).
// ws layout (bytes): Hh[0,128M) Hl[128M,256M) Uh Ul msq  => total 270,536,704 B.

typedef unsigned short u16;
typedef __attribute__((ext_vector_type(8))) short short8;   // 8 x bf16
typedef __attribute__((ext_vector_type(4))) float f32x4;

#define B_DIM 64
#define DIM   512
#define T_DIM 2048
#define S_DIM 1024

#define SLAB_BYTES 49152        // Ah 16K | Al 16K | Bh 8K | Bl 8K
#define AL_OFF 16384
#define BH_OFF 32768
#define BL_OFF 40960

__device__ __forceinline__ u16 f32_to_bf16(float f) {
  uint32_t u = __float_as_uint(f);
  uint32_t r = u + 0x7FFFu + ((u >> 16) & 1u);   // RNE
  return (u16)(r >> 16);
}
__device__ __forceinline__ float bf16_to_f32(u16 h) {
  return __uint_as_float(((uint32_t)h) << 16);
}

// ---------------- K0a: units -> U^T hi/lo + msq ----------------
__global__ __launch_bounds__(256) void k_prep_units(const float* __restrict__ units,
                                                    u16* __restrict__ Uh, u16* __restrict__ Ul,
                                                    float* __restrict__ msq) {
  const int s0 = blockIdx.x * 4;
  const int tid = threadIdx.x;
  const int lane = tid & 63, wv = tid >> 6;
  float acc0 = 0.f, acc1 = 0.f, acc2 = 0.f, acc3 = 0.f;
#pragma unroll
  for (int j = 0; j < 2; ++j) {
    const int d = tid + j * 256;
    const float4 v = *(const float4*)(units + (size_t)d * S_DIM + s0);
    acc0 += v.x * v.x; acc1 += v.y * v.y; acc2 += v.z * v.z; acc3 += v.w * v.w;
    u16 h;
    h = f32_to_bf16(v.x); Uh[(s0 + 0) * DIM + d] = h; Ul[(s0 + 0) * DIM + d] = f32_to_bf16(v.x - bf16_to_f32(h));
    h = f32_to_bf16(v.y); Uh[(s0 + 1) * DIM + d] = h; Ul[(s0 + 1) * DIM + d] = f32_to_bf16(v.y - bf16_to_f32(h));
    h = f32_to_bf16(v.z); Uh[(s0 + 2) * DIM + d] = h; Ul[(s0 + 2) * DIM + d] = f32_to_bf16(v.z - bf16_to_f32(h));
    h = f32_to_bf16(v.w); Uh[(s0 + 3) * DIM + d] = h; Ul[(s0 + 3) * DIM + d] = f32_to_bf16(v.w - bf16_to_f32(h));
  }
#pragma unroll
  for (int off = 1; off < 64; off <<= 1) {
    acc0 += __shfl_xor(acc0, off);
    acc1 += __shfl_xor(acc1, off);
    acc2 += __shfl_xor(acc2, off);
    acc3 += __shfl_xor(acc3, off);
  }
  __shared__ float part[4][4];
  if (lane == 0) { part[wv][0] = acc0; part[wv][1] = acc1; part[wv][2] = acc2; part[wv][3] = acc3; }
  __syncthreads();
  if (tid < 4) msq[s0 + tid] = part[0][tid] + part[1][tid] + part[2][tid] + part[3][tid];
}

// ---------------- K0b: H [b][d][t] -> H^T hi/lo [b][t][d] ----------------
__global__ __launch_bounds__(256) void k_prep_h(const float* __restrict__ H,
                                                u16* __restrict__ Hh, u16* __restrict__ Hl) {
  __shared__ float tile[64 * 68];
  const int t0 = blockIdx.x * 64, d0 = blockIdx.y * 64, b = blockIdx.z;
  const int tid = threadIdx.x;
#pragma unroll
  for (int j = 0; j < 4; ++j) {
    const int chunk = tid + j * 256;
    const int r = chunk >> 4, c4 = (chunk & 15) * 4;
    const float4 v = *(const float4*)(H + ((size_t)(b * DIM + d0 + r)) * T_DIM + t0 + c4);
    *(float4*)(&tile[r * 68 + c4]) = v;
  }
  __syncthreads();
#pragma unroll
  for (int j = 0; j < 2; ++j) {
    const int chunk = tid + j * 256;
    const int q = chunk >> 3, e8i = chunk & 7, e8 = e8i * 8;
    union { u16 us[8]; uint4 v4; } hi, lo;
#pragma unroll
    for (int s = 0; s < 8; ++s) {
      const int kk = s ^ e8i;                        // spread banks across e8 groups
      const float f = tile[(e8 + kk) * 68 + q];
      const u16 h = f32_to_bf16(f);
      hi.us[kk] = h;
      lo.us[kk] = f32_to_bf16(f - bf16_to_f32(h));
    }
    const size_t o = ((size_t)(b * T_DIM + t0 + q)) * DIM + d0 + e8;
    *(uint4*)(Hh + o) = hi.v4;
    *(uint4*)(Hl + o) = lo.v4;
  }
}

// ---------------- K1: GEMM ----------------
__device__ __forceinline__ void gl_lds16(const void* g, void* l) {
  __builtin_amdgcn_global_load_lds((const __attribute__((address_space(1))) void*)g,
                                   (__attribute__((address_space(3))) void*)l, 16, 0, 0);
}

struct StageCtx {
  const char *pUh, *pUl, *pHh, *pHl;
  size_t aOff0, aOff1, bOff;
  int dA0, dB;
};

__device__ __forceinline__ void stage_slab(char* slab, const StageCtx& c, size_t ko) {
  gl_lds16(c.pUh + c.aOff0 + ko, slab + c.dA0);
  gl_lds16(c.pUh + c.aOff1 + ko, slab + c.dA0 + 8192);
  gl_lds16(c.pUl + c.aOff0 + ko, slab + c.dA0 + AL_OFF);
  gl_lds16(c.pUl + c.aOff1 + ko, slab + c.dA0 + AL_OFF + 8192);
  gl_lds16(c.pHh + c.bOff + ko, slab + c.dB);
  gl_lds16(c.pHl + c.bOff + ko, slab + c.dB + 8192);
}

__device__ __forceinline__ void compute_slab(const char* slab, const int* offA, const int* offB,
                                             f32x4 (&acc)[4][4]) {
  short8 ah[4], al[4], bh[4], bl[4];
#pragma unroll
  for (int i = 0; i < 4; ++i) {
    ah[i] = *(const short8*)(slab + offA[i]);
    al[i] = *(const short8*)(slab + offA[i] + AL_OFF);
  }
#pragma unroll
  for (int i = 0; i < 4; ++i) {
    bh[i] = *(const short8*)(slab + offB[i]);
    bl[i] = *(const short8*)(slab + offB[i] + 8192);
  }
  __builtin_amdgcn_s_setprio(1);
#pragma unroll
  for (int mt = 0; mt < 4; ++mt)
#pragma unroll
    for (int nt = 0; nt < 4; ++nt) {
      acc[mt][nt] = __builtin_amdgcn_mfma_f32_16x16x32_bf16(ah[mt], bh[nt], acc[mt][nt], 0, 0, 0);
      acc[mt][nt] = __builtin_amdgcn_mfma_f32_16x16x32_bf16(ah[mt], bl[nt], acc[mt][nt], 0, 0, 0);
      acc[mt][nt] = __builtin_amdgcn_mfma_f32_16x16x32_bf16(al[mt], bh[nt], acc[mt][nt], 0, 0, 0);
    }
  __builtin_amdgcn_s_setprio(0);
}

#define WAITV(N) asm volatile("s_waitcnt vmcnt(" #N ")" ::: "memory")
#define BAR()    do { __builtin_amdgcn_s_barrier(); __builtin_amdgcn_sched_barrier(0); } while (0)

__global__ __launch_bounds__(512, 2) void k_gemm(const u16* __restrict__ Uh, const u16* __restrict__ Ul,
                                                 const u16* __restrict__ Hh, const u16* __restrict__ Hl,
                                                 float* __restrict__ out) {
  __shared__ char smem[3 * SLAB_BYTES];   // 144 KB: 3-slot ring
  const int tid = threadIdx.x;
  const int lane = tid & 63, wv = tid >> 6;

  // T1: bijective XCD swizzle (nwg=4096, 4096%8==0). s innermost per XCD chunk.
  const int bid = blockIdx.x;
  const int wg = (bid & 7) * 512 + (bid >> 3);
  const int s0 = (wg & 3) * 256;
  const int t0 = ((wg >> 2) & 15) * 128;
  const int bb = wg >> 6;

  // Staging context (src-addr XOR swizzle keeps LDS linear; chunk' = chunk ^ ((row>>1)&3))
  const int c = tid & 3;
  const int r0 = tid >> 2;                       // 0..127
  const int cs = c ^ ((r0 >> 1) & 3);
  StageCtx ctx;
  ctx.pUh = (const char*)Uh; ctx.pUl = (const char*)Ul;
  ctx.pHh = (const char*)Hh; ctx.pHl = (const char*)Hl;
  ctx.aOff0 = (size_t)(s0 + r0) * 1024 + (size_t)cs * 16;       // row stride 512*2B
  ctx.aOff1 = ctx.aOff0 + (size_t)128 * 1024;                   // rows +128, same cs
  ctx.bOff  = ((size_t)bb * T_DIM + t0 + r0) * 1024 + (size_t)cs * 16;
  ctx.dA0 = tid * 16;
  ctx.dB  = BH_OFF + tid * 16;

  // Fragment read offsets (swizzled chunk index), wave = (wm 0..3 of M, wn 0..1 of N)
  const int wm = wv >> 1, wn = wv & 1;
  int offA[4], offB[4];
#pragma unroll
  for (int mt = 0; mt < 4; ++mt) {
    const int row = wm * 64 + mt * 16 + (lane & 15);
    const int cidx = (lane >> 4) ^ ((row >> 1) & 3);
    offA[mt] = row * 64 + cidx * 16;
  }
#pragma unroll
  for (int nt = 0; nt < 4; ++nt) {
    const int row = wn * 64 + nt * 16 + (lane & 15);
    const int cidx = (lane >> 4) ^ ((row >> 1) & 3);
    offB[nt] = BH_OFF + row * 64 + cidx * 16;
  }

  f32x4 acc[4][4];
#pragma unroll
  for (int i = 0; i < 4; ++i)
#pragma unroll
    for (int j = 0; j < 4; ++j)
      acc[i][j] = (f32x4){0.f, 0.f, 0.f, 0.f};

  // Prologue: 3 slabs in flight (18 loads/wave)
  stage_slab(smem + 0 * SLAB_BYTES, ctx, 0 * 64);
  stage_slab(smem + 1 * SLAB_BYTES, ctx, 1 * 64);
  stage_slab(smem + 2 * SLAB_BYTES, ctx, 2 * 64);

  int slot = 0;
#pragma unroll 1
  for (int k = 0; k < 13; ++k) {
    WAITV(12);                      // drain slab k (6), leave k+1,k+2 (12) in flight
    BAR();
    char* slab = smem + slot * SLAB_BYTES;
    compute_slab(slab, offA, offB, acc);
    BAR();                          // all waves done reading slot
    stage_slab(slab, ctx, (size_t)(k + 3) * 64);
    slot = (slot == 2) ? 0 : slot + 1;
  }
  // k=13: outstanding 13,14,15 -> wait to 12 drains slab 13; no restage
  WAITV(12);
  BAR();
  compute_slab(smem + slot * SLAB_BYTES, offA, offB, acc);
  slot = (slot == 2) ? 0 : slot + 1;
  // k=14: outstanding 14,15 (12) -> wait to 6 drains slab 14
  WAITV(6);
  BAR();
  compute_slab(smem + slot * SLAB_BYTES, offA, offB, acc);
  slot = (slot == 2) ? 0 : slot + 1;
  // k=15
  WAITV(0);
  BAR();
  compute_slab(smem + slot * SLAB_BYTES, offA, offB, acc);

  // C/D 16x16x32: col = lane&15 (t), row = (lane>>4)*4 + reg (s)
  float* const outb = out + (size_t)bb * ((size_t)S_DIM * T_DIM);
  const int tcol = t0 + wn * 64 + (lane & 15);
  const int sbase = s0 + wm * 64 + (lane >> 4) * 4;
#pragma unroll
  for (int mt = 0; mt < 4; ++mt)
#pragma unroll
    for (int nt = 0; nt < 4; ++nt)
#pragma unroll
      for (int r = 0; r < 4; ++r)
        outb[(size_t)(sbase + mt * 16 + r) * T_DIM + tcol + nt * 16] = acc[mt][nt][r];
}

// ---------------- K2: in-place softmax over s ----------------
__global__ __launch_bounds__(256) void k_softmax(float* __restrict__ out, const float* __restrict__ msq) {
  const int t0 = blockIdx.x * 16, b = blockIdx.y;
  const int tid = threadIdx.x;
  const int lane = tid & 63, wv = tid >> 6;
  const int c = tid & 3;
  const int g = tid >> 2;
  float* const base = out + (size_t)b * ((size_t)S_DIM * T_DIM) + t0 + c * 4;

  float4 l[16];
  float4 m = {-3.0e38f, -3.0e38f, -3.0e38f, -3.0e38f};
#pragma unroll
  for (int i = 0; i < 16; ++i) {
    const int s = g + i * 64;
    const float4 v = *(const float4*)(base + (size_t)s * T_DIM);
    const float mq = msq[s];
    float4 L;
    L.x = 2.f * v.x - mq; L.y = 2.f * v.y - mq; L.z = 2.f * v.z - mq; L.w = 2.f * v.w - mq;
    l[i] = L;
    m.x = fmaxf(m.x, L.x); m.y = fmaxf(m.y, L.y); m.z = fmaxf(m.z, L.z); m.w = fmaxf(m.w, L.w);
  }
#pragma unroll
  for (int off = 4; off < 64; off <<= 1) {
    m.x = fmaxf(m.x, __shfl_xor(m.x, off));
    m.y = fmaxf(m.y, __shfl_xor(m.y, off));
    m.z = fmaxf(m.z, __shfl_xor(m.z, off));
    m.w = fmaxf(m.w, __shfl_xor(m.w, off));
  }
  __shared__ float4 redM[4][4];
  __shared__ float4 redS[4][4];
  if (lane < 4) redM[wv][lane] = m;
  __syncthreads();
  float4 M = redM[0][c];
#pragma unroll
  for (int w = 1; w < 4; ++w) {
    const float4 o = redM[w][c];
    M.x = fmaxf(M.x, o.x); M.y = fmaxf(M.y, o.y); M.z = fmaxf(M.z, o.z); M.w = fmaxf(M.w, o.w);
  }
  float4 ssum = {0.f, 0.f, 0.f, 0.f};
#pragma unroll
  for (int i = 0; i < 16; ++i) {
    float4 e;
    e.x = __expf(l[i].x - M.x);
    e.y = __expf(l[i].y - M.y);
    e.z = __expf(l[i].z - M.z);
    e.w = __expf(l[i].w - M.w);
    l[i] = e;
    ssum.x += e.x; ssum.y += e.y; ssum.z += e.z; ssum.w += e.w;
  }
#pragma unroll
  for (int off = 4; off < 64; off <<= 1) {
    ssum.x += __shfl_xor(ssum.x, off);
    ssum.y += __shfl_xor(ssum.y, off);
    ssum.z += __shfl_xor(ssum.z, off);
    ssum.w += __shfl_xor(ssum.w, off);
  }
  if (lane < 4) redS[wv][lane] = ssum;
  __syncthreads();
  float4 S = redS[0][c];
#pragma unroll
  for (int w = 1; w < 4; ++w) {
    const float4 o = redS[w][c];
    S.x += o.x; S.y += o.y; S.z += o.z; S.w += o.w;
  }
  float4 rs;
  rs.x = 1.0f / S.x; rs.y = 1.0f / S.y; rs.z = 1.0f / S.z; rs.w = 1.0f / S.w;
#pragma unroll
  for (int i = 0; i < 16; ++i) {
    const int s = g + i * 64;
    float4 o;
    o.x = l[i].x * rs.x; o.y = l[i].y * rs.y; o.z = l[i].z * rs.z; o.w = l[i].w * rs.w;
    *(float4*)(base + (size_t)s * T_DIM) = o;
  }
}

// ---------------- launch ----------------
extern "C" void kernel_launch(void* const* d_in, const int* in_sizes, int n_in,
                              void* d_out, int out_size, void* d_ws, size_t ws_size,
                              hipStream_t stream) {
  (void)in_sizes; (void)n_in; (void)out_size; (void)ws_size;
  const float* H = (const float*)d_in[0];
  const float* units = (const float*)d_in[1];
  float* out = (float*)d_out;
  char* ws = (char*)d_ws;
  u16* Hh = (u16*)(ws);
  u16* Hl = (u16*)(ws + 134217728);
  u16* Uh = (u16*)(ws + 268435456);
  u16* Ul = (u16*)(ws + 269484032);
  float* msq = (float*)(ws + 270532608);

  k_prep_units<<<dim3(S_DIM / 4), 256, 0, stream>>>(units, Uh, Ul, msq);
  k_prep_h<<<dim3(T_DIM / 64, DIM / 64, B_DIM), 256, 0, stream>>>(H, Hh, Hl);
  k_gemm<<<dim3((S_DIM / 256) * (T_DIM / 128) * B_DIM), 512, 0, stream>>>(Uh, Ul, Hh, Hl, out);
  k_softmax<<<dim3(T_DIM / 16, B_DIM), 256, 0, stream>>>(out, msq);
}

// Round 3
// 795.182 us; speedup vs baseline: 1.2257x; 1.2257x over previous
//
#include <hip/hip_runtime.h>
#include <stdint.h>

// Problem: B=64, DIM=512, T=2048, S=1024.
// out[b][s][t] = softmax_s( 2*cross - msq[s] ),  cross = sum_d units[d][s]*H[b][d][t].
// k_gemm: 256x256 tile, BK=32, 2x64KB LDS dbuf, 3 product-phases/slab
// (AhBh, AhBl, AlBh), counted vmcnt ladder 4/6/6 (T3+T4), setprio (T5),
// bijective XCD swizzle (T1), src-addr XOR swizzle (T2-equivalent, 0 conflicts).
// ws layout: Hh[0,128M) Hl[128M,256M) Uh Ul msq => 270,536,704 B.

typedef unsigned short u16;
typedef __attribute__((ext_vector_type(8))) short short8;   // 8 x bf16
typedef __attribute__((ext_vector_type(4))) float f32x4;

#define B_DIM 64
#define DIM   512
#define T_DIM 2048
#define S_DIM 1024

#define SLOT  65536
#define AH_O  0
#define AL_O  16384
#define BH_O  32768
#define BL_O  49152

__device__ __forceinline__ u16 f32_to_bf16(float f) {
  uint32_t u = __float_as_uint(f);
  uint32_t r = u + 0x7FFFu + ((u >> 16) & 1u);   // RNE
  return (u16)(r >> 16);
}
__device__ __forceinline__ float bf16_to_f32(u16 h) {
  return __uint_as_float(((uint32_t)h) << 16);
}

// ---------------- K0a: units -> U^T hi/lo + msq ----------------
__global__ __launch_bounds__(256) void k_prep_units(const float* __restrict__ units,
                                                    u16* __restrict__ Uh, u16* __restrict__ Ul,
                                                    float* __restrict__ msq) {
  const int s0 = blockIdx.x * 4;
  const int tid = threadIdx.x;
  const int lane = tid & 63, wv = tid >> 6;
  float acc0 = 0.f, acc1 = 0.f, acc2 = 0.f, acc3 = 0.f;
#pragma unroll
  for (int j = 0; j < 2; ++j) {
    const int d = tid + j * 256;
    const float4 v = *(const float4*)(units + (size_t)d * S_DIM + s0);
    acc0 += v.x * v.x; acc1 += v.y * v.y; acc2 += v.z * v.z; acc3 += v.w * v.w;
    u16 h;
    h = f32_to_bf16(v.x); Uh[(s0 + 0) * DIM + d] = h; Ul[(s0 + 0) * DIM + d] = f32_to_bf16(v.x - bf16_to_f32(h));
    h = f32_to_bf16(v.y); Uh[(s0 + 1) * DIM + d] = h; Ul[(s0 + 1) * DIM + d] = f32_to_bf16(v.y - bf16_to_f32(h));
    h = f32_to_bf16(v.z); Uh[(s0 + 2) * DIM + d] = h; Ul[(s0 + 2) * DIM + d] = f32_to_bf16(v.z - bf16_to_f32(h));
    h = f32_to_bf16(v.w); Uh[(s0 + 3) * DIM + d] = h; Ul[(s0 + 3) * DIM + d] = f32_to_bf16(v.w - bf16_to_f32(h));
  }
#pragma unroll
  for (int off = 1; off < 64; off <<= 1) {
    acc0 += __shfl_xor(acc0, off);
    acc1 += __shfl_xor(acc1, off);
    acc2 += __shfl_xor(acc2, off);
    acc3 += __shfl_xor(acc3, off);
  }
  __shared__ float part[4][4];
  if (lane == 0) { part[wv][0] = acc0; part[wv][1] = acc1; part[wv][2] = acc2; part[wv][3] = acc3; }
  __syncthreads();
  if (tid < 4) msq[s0 + tid] = part[0][tid] + part[1][tid] + part[2][tid] + part[3][tid];
}

// ---------------- K0b: H [b][d][t] -> H^T hi/lo [b][t][d] ----------------
__global__ __launch_bounds__(256) void k_prep_h(const float* __restrict__ H,
                                                u16* __restrict__ Hh, u16* __restrict__ Hl) {
  __shared__ float tile[64 * 68];
  const int t0 = blockIdx.x * 64, d0 = blockIdx.y * 64, b = blockIdx.z;
  const int tid = threadIdx.x;
#pragma unroll
  for (int j = 0; j < 4; ++j) {
    const int chunk = tid + j * 256;
    const int r = chunk >> 4, c4 = (chunk & 15) * 4;
    const float4 v = *(const float4*)(H + ((size_t)(b * DIM + d0 + r)) * T_DIM + t0 + c4);
    *(float4*)(&tile[r * 68 + c4]) = v;
  }
  __syncthreads();
#pragma unroll
  for (int j = 0; j < 2; ++j) {
    const int chunk = tid + j * 256;
    const int q = chunk >> 3, e8 = (chunk & 7) * 8;
    union { u16 us[8]; uint4 v4; } hi, lo;
#pragma unroll
    for (int k = 0; k < 8; ++k) {
      const float f = tile[(e8 + k) * 68 + q];
      const u16 h = f32_to_bf16(f);
      hi.us[k] = h;
      lo.us[k] = f32_to_bf16(f - bf16_to_f32(h));
    }
    const size_t o = ((size_t)(b * T_DIM + t0 + q)) * DIM + d0 + e8;
    *(uint4*)(Hh + o) = hi.v4;
    *(uint4*)(Hl + o) = lo.v4;
  }
}

// ---------------- K1: GEMM ----------------
__device__ __forceinline__ void gl16(const void* g, void* l) {
  __builtin_amdgcn_global_load_lds((const __attribute__((address_space(1))) void*)g,
                                   (__attribute__((address_space(3))) void*)l, 16, 0, 0);
}

#define WAITV(N) asm volatile("s_waitcnt vmcnt(" #N ")" ::: "memory")
#define SYNCPT() do { __builtin_amdgcn_s_barrier(); __builtin_amdgcn_sched_barrier(0); } while (0)
#define LGKM0()  do { asm volatile("s_waitcnt lgkmcnt(0)" ::: "memory"); __builtin_amdgcn_sched_barrier(0); } while (0)

// stage 2 chunks of one matrix stream (per wave: 2 x 1KB = its share of a 16KB tile)
#define ST_A(P, MO, SL, KO) do { \
  gl16((P) + aO0 + (KO), sm + (SL) + (MO) + dA0); \
  gl16((P) + aO1 + (KO), sm + (SL) + (MO) + dA1); } while (0)
#define ST_B(P, MO, SL, KO) do { \
  gl16((P) + bO0 + (KO), sm + (SL) + (MO) + dA0); \
  gl16((P) + bO1 + (KO), sm + (SL) + (MO) + dA1); } while (0)

__global__ __launch_bounds__(512, 2) void k_gemm(const u16* __restrict__ Uh, const u16* __restrict__ Ul,
                                                 const u16* __restrict__ Hh, const u16* __restrict__ Hl,
                                                 float* __restrict__ out) {
  __shared__ __align__(16) char sm[2 * SLOT];   // 128 KB
  const int tid = threadIdx.x;
  const int lane = tid & 63, wv = tid >> 6;
  const int wm = wv >> 2, wn = wv & 3;          // 2M x 4N waves, wave tile 128x64

  // T1: bijective XCD swizzle (nwg=2048, %8==0). s innermost per XCD chunk.
  const int bid = blockIdx.x;
  const int wg = (bid & 7) * 256 + (bid >> 3);
  const int s0 = (wg & 3) * 256;
  const int t0 = ((wg >> 2) & 7) * 256;
  const int bb = wg >> 5;

  // Staging: per matrix 1024 16B-chunks; wave wv owns chunks [wv*128, wv*128+128) as 2 insts.
  // Source addr carries XOR swizzle (chunk' = c ^ ((row>>1)&3)); LDS dest linear.
  const int ch0 = wv * 128 + lane, ch1 = ch0 + 64;
  const int r0 = ch0 >> 2, r1 = ch1 >> 2;
  const int cs0 = ((ch0 & 3) ^ (r0 >> 1)) & 3;
  const int cs1 = ((ch1 & 3) ^ (r1 >> 1)) & 3;
  const size_t aO0 = (size_t)(s0 + r0) * 1024 + (size_t)cs0 * 16;  // row stride 512*2B
  const size_t aO1 = (size_t)(s0 + r1) * 1024 + (size_t)cs1 * 16;
  const size_t bO0 = ((size_t)(bb * T_DIM + t0 + r0)) * 1024 + (size_t)cs0 * 16;
  const size_t bO1 = ((size_t)(bb * T_DIM + t0 + r1)) * 1024 + (size_t)cs1 * 16;
  const int dA0 = wv * 2048, dA1 = wv * 2048 + 1024;   // wave-uniform LDS dest bases

  const char* pAh = (const char*)Uh;
  const char* pAl = (const char*)Ul;
  const char* pBh = (const char*)Hh;
  const char* pBl = (const char*)Hl;

  // Fragment read offsets: row*64 + cidx*16 (+ mt*1024); cidx lane-const since (mt*16>>1)&3==0
  const int rA = wm * 128 + (lane & 15);
  const int offA = rA * 64 + ((((lane >> 4) ^ (rA >> 1)) & 3) << 4);
  const int rB = wn * 64 + (lane & 15);
  const int offB = rB * 64 + ((((lane >> 4) ^ (rB >> 1)) & 3) << 4);

  f32x4 acc[8][4];
#pragma unroll
  for (int i = 0; i < 8; ++i)
#pragma unroll
    for (int j = 0; j < 4; ++j)
      acc[i][j] = (f32x4){0.f, 0.f, 0.f, 0.f};

  // Prologue: stage slab 0 in ladder order [Ah,Bh | Bl | Al]  (8 insts/wave)
  ST_A(pAh, AH_O, 0, 0);
  ST_B(pBh, BH_O, 0, 0);
  ST_B(pBl, BL_O, 0, 0);
  ST_A(pAl, AL_O, 0, 0);

  // Per-slab: 3 phases. WAITV -> barrier (cross-wave landed) -> reads + next-slab issues
  //           -> lgkmcnt(0) -> setprio(1) MFMA x32 setprio(0).
#define PHASE1(CUR, NXT, STG, KO)                                              \
  {                                                                            \
    SYNCPT();                                                                  \
    _Pragma("unroll") for (int mt = 0; mt < 8; ++mt)                           \
      ah[mt] = *(const short8*)(sm + (CUR) + AH_O + offA + mt * 1024);         \
    short8 bh[4];                                                              \
    _Pragma("unroll") for (int nt = 0; nt < 4; ++nt)                           \
      bh[nt] = *(const short8*)(sm + (CUR) + BH_O + offB + nt * 1024);         \
    if (STG) { ST_A(pAh, AH_O, NXT, KO); ST_B(pBh, BH_O, NXT, KO); }           \
    LGKM0();                                                                   \
    __builtin_amdgcn_s_setprio(1);                                             \
    _Pragma("unroll") for (int mt = 0; mt < 8; ++mt)                           \
      _Pragma("unroll") for (int nt = 0; nt < 4; ++nt)                         \
        acc[mt][nt] = __builtin_amdgcn_mfma_f32_16x16x32_bf16(ah[mt], bh[nt], acc[mt][nt], 0, 0, 0); \
    __builtin_amdgcn_s_setprio(0);                                             \
  }
#define PHASE2(CUR, NXT, STG, KO)                                              \
  {                                                                            \
    SYNCPT();                                                                  \
    short8 bl[4];                                                              \
    _Pragma("unroll") for (int nt = 0; nt < 4; ++nt)                           \
      bl[nt] = *(const short8*)(sm + (CUR) + BL_O + offB + nt * 1024);         \
    if (STG) { ST_B(pBl, BL_O, NXT, KO); }                                     \
    LGKM0();                                                                   \
    __builtin_amdgcn_s_setprio(1);                                             \
    _Pragma("unroll") for (int mt = 0; mt < 8; ++mt)                           \
      _Pragma("unroll") for (int nt = 0; nt < 4; ++nt)                         \
        acc[mt][nt] = __builtin_amdgcn_mfma_f32_16x16x32_bf16(ah[mt], bl[nt], acc[mt][nt], 0, 0, 0); \
    __builtin_amdgcn_s_setprio(0);                                             \
  }
#define PHASE3(CUR, NXT, STG, KO)                                              \
  {                                                                            \
    SYNCPT();                                                                  \
    short8 al[8], bh2[4];                                                      \
    _Pragma("unroll") for (int mt = 0; mt < 8; ++mt)                           \
      al[mt] = *(const short8*)(sm + (CUR) + AL_O + offA + mt * 1024);         \
    _Pragma("unroll") for (int nt = 0; nt < 4; ++nt)                           \
      bh2[nt] = *(const short8*)(sm + (CUR) + BH_O + offB + nt * 1024);        \
    if (STG) { ST_A(pAl, AL_O, NXT, KO); }                                     \
    LGKM0();                                                                   \
    __builtin_amdgcn_s_setprio(1);                                             \
    _Pragma("unroll") for (int mt = 0; mt < 8; ++mt)                           \
      _Pragma("unroll") for (int nt = 0; nt < 4; ++nt)                         \
        acc[mt][nt] = __builtin_amdgcn_mfma_f32_16x16x32_bf16(al[mt], bh2[nt], acc[mt][nt], 0, 0, 0); \
    __builtin_amdgcn_s_setprio(0);                                             \
  }

#pragma unroll 1
  for (int k = 0; k < 15; ++k) {
    const int cur = (k & 1) * SLOT;
    const int nxt = SLOT - cur;
    const size_t ko = (size_t)(k + 1) * 64;
    short8 ah[8];
    WAITV(4);  PHASE1(cur, nxt, 1, ko);   // drains Ah,Bh(k); leaves Bl,Al(k)
    WAITV(6);  PHASE2(cur, nxt, 1, ko);   // drains Bl(k)
    WAITV(6);  PHASE3(cur, nxt, 1, ko);   // drains Al(k)
  }
  {
    const int cur = SLOT;   // k=15 slot
    short8 ah[8];
    WAITV(4);  PHASE1(cur, 0, 0, 0);
    WAITV(2);  PHASE2(cur, 0, 0, 0);
    WAITV(0);  PHASE3(cur, 0, 0, 0);
  }

  // C/D 16x16x32: col = lane&15 (t), row = (lane>>4)*4 + reg (s)
  float* const outb = out + (size_t)bb * ((size_t)S_DIM * T_DIM);
  const int tcol = t0 + wn * 64 + (lane & 15);
  const int sbase = s0 + wm * 128 + (lane >> 4) * 4;
#pragma unroll
  for (int mt = 0; mt < 8; ++mt)
#pragma unroll
    for (int nt = 0; nt < 4; ++nt)
#pragma unroll
      for (int r = 0; r < 4; ++r)
        outb[(size_t)(sbase + mt * 16 + r) * T_DIM + tcol + nt * 16] = acc[mt][nt][r];
}

// ---------------- K2: in-place softmax over s ----------------
__global__ __launch_bounds__(256) void k_softmax(float* __restrict__ out, const float* __restrict__ msq) {
  const int t0 = blockIdx.x * 16, b = blockIdx.y;
  const int tid = threadIdx.x;
  const int lane = tid & 63, wv = tid >> 6;
  const int c = tid & 3;
  const int g = tid >> 2;
  float* const base = out + (size_t)b * ((size_t)S_DIM * T_DIM) + t0 + c * 4;

  float4 l[16];
  float4 m = {-3.0e38f, -3.0e38f, -3.0e38f, -3.0e38f};
#pragma unroll
  for (int i = 0; i < 16; ++i) {
    const int s = g + i * 64;
    const float4 v = *(const float4*)(base + (size_t)s * T_DIM);
    const float mq = msq[s];
    float4 L;
    L.x = 2.f * v.x - mq; L.y = 2.f * v.y - mq; L.z = 2.f * v.z - mq; L.w = 2.f * v.w - mq;
    l[i] = L;
    m.x = fmaxf(m.x, L.x); m.y = fmaxf(m.y, L.y); m.z = fmaxf(m.z, L.z); m.w = fmaxf(m.w, L.w);
  }
#pragma unroll
  for (int off = 4; off < 64; off <<= 1) {
    m.x = fmaxf(m.x, __shfl_xor(m.x, off));
    m.y = fmaxf(m.y, __shfl_xor(m.y, off));
    m.z = fmaxf(m.z, __shfl_xor(m.z, off));
    m.w = fmaxf(m.w, __shfl_xor(m.w, off));
  }
  __shared__ float4 redM[4][4];
  __shared__ float4 redS[4][4];
  if (lane < 4) redM[wv][lane] = m;
  __syncthreads();
  float4 M = redM[0][c];
#pragma unroll
  for (int w = 1; w < 4; ++w) {
    const float4 o = redM[w][c];
    M.x = fmaxf(M.x, o.x); M.y = fmaxf(M.y, o.y); M.z = fmaxf(M.z, o.z); M.w = fmaxf(M.w, o.w);
  }
  float4 ssum = {0.f, 0.f, 0.f, 0.f};
#pragma unroll
  for (int i = 0; i < 16; ++i) {
    float4 e;
    e.x = __expf(l[i].x - M.x);
    e.y = __expf(l[i].y - M.y);
    e.z = __expf(l[i].z - M.z);
    e.w = __expf(l[i].w - M.w);
    l[i] = e;
    ssum.x += e.x; ssum.y += e.y; ssum.z += e.z; ssum.w += e.w;
  }
#pragma unroll
  for (int off = 4; off < 64; off <<= 1) {
    ssum.x += __shfl_xor(ssum.x, off);
    ssum.y += __shfl_xor(ssum.y, off);
    ssum.z += __shfl_xor(ssum.z, off);
    ssum.w += __shfl_xor(ssum.w, off);
  }
  if (lane < 4) redS[wv][lane] = ssum;
  __syncthreads();
  float4 S = redS[0][c];
#pragma unroll
  for (int w = 1; w < 4; ++w) {
    const float4 o = redS[w][c];
    S.x += o.x; S.y += o.y; S.z += o.z; S.w += o.w;
  }
  float4 rs;
  rs.x = 1.0f / S.x; rs.y = 1.0f / S.y; rs.z = 1.0f / S.z; rs.w = 1.0f / S.w;
#pragma unroll
  for (int i = 0; i < 16; ++i) {
    const int s = g + i * 64;
    float4 o;
    o.x = l[i].x * rs.x; o.y = l[i].y * rs.y; o.z = l[i].z * rs.z; o.w = l[i].w * rs.w;
    *(float4*)(base + (size_t)s * T_DIM) = o;
  }
}

// ---------------- launch ----------------
extern "C" void kernel_launch(void* const* d_in, const int* in_sizes, int n_in,
                              void* d_out, int out_size, void* d_ws, size_t ws_size,
                              hipStream_t stream) {
  (void)in_sizes; (void)n_in; (void)out_size; (void)ws_size;
  const float* H = (const float*)d_in[0];
  const float* units = (const float*)d_in[1];
  float* out = (float*)d_out;
  char* ws = (char*)d_ws;
  u16* Hh = (u16*)(ws);
  u16* Hl = (u16*)(ws + 134217728);
  u16* Uh = (u16*)(ws + 268435456);
  u16* Ul = (u16*)(ws + 269484032);
  float* msq = (float*)(ws + 270532608);

  k_prep_units<<<dim3(S_DIM / 4), 256, 0, stream>>>(units, Uh, Ul, msq);
  k_prep_h<<<dim3(T_DIM / 64, DIM / 64, B_DIM), 256, 0, stream>>>(H, Hh, Hl);
  k_gemm<<<dim3((S_DIM / 256) * (T_DIM / 256) * B_DIM), 512, 0, stream>>>(Uh, Ul, Hh, Hl, out);
  k_softmax<<<dim3(T_DIM / 16, B_DIM), 256, 0, stream>>>(out, msq);
}

// Round 4
// 680.058 us; speedup vs baseline: 1.4332x; 1.1693x over previous
//
#include <hip/hip_runtime.h>
#include <stdint.h>

// Problem: B=64, DIM=512, T=2048, S=1024.
// out[b][s][t] = softmax_s( 2*cross - msq[s] ),  cross = sum_d units[d][s]*H[b][d][t].
// Pipeline:
//   k_prep_units: units fp32 -> U^T bf16 hi/lo [s][d] in ws, + msq[s].
//   k_prep_h:     H fp32 [b][d][t] -> H^T bf16 hi/lo [b][t][d] in ws (LDS transpose).
//   k_fused:      FULL-S GEMM (1024 x 64 per block) + in-register softmax epilogue
//                 -> writes final probabilities. No logits ever touch HBM.
//                 3x bf16 MFMA hi/lo split, 3-slot LDS ring, counted vmcnt(10),
//                 setprio, src-addr XOR swizzle (0 conflicts, R3-verified layouts).
// ws layout: Hh[0,128M) Hl[128M,256M) Uh Ul msq => 270,536,704 B.

typedef unsigned short u16;
typedef __attribute__((ext_vector_type(8))) short short8;   // 8 x bf16
typedef __attribute__((ext_vector_type(4))) float f32x4;

#define B_DIM 64
#define DIM   512
#define T_DIM 2048
#define S_DIM 1024

// fused-kernel LDS map (bytes)
#define SLOT   40960          // Ah 16K | Al 16K | Bh 4K | Bl 4K
#define A_LO   16384
#define B_HI   32768
#define B_LO   36864
#define MSQ_O  122880         // 3*SLOT
#define REDM_O 126976
#define REDS_O 128000
#define SM_SZ  129024

__device__ __forceinline__ u16 f32_to_bf16(float f) {
  uint32_t u = __float_as_uint(f);
  uint32_t r = u + 0x7FFFu + ((u >> 16) & 1u);   // RNE
  return (u16)(r >> 16);
}
__device__ __forceinline__ float bf16_to_f32(u16 h) {
  return __uint_as_float(((uint32_t)h) << 16);
}

// ---------------- K0a: units -> U^T hi/lo + msq ----------------
__global__ __launch_bounds__(256) void k_prep_units(const float* __restrict__ units,
                                                    u16* __restrict__ Uh, u16* __restrict__ Ul,
                                                    float* __restrict__ msq) {
  const int s0 = blockIdx.x * 4;
  const int tid = threadIdx.x;
  const int lane = tid & 63, wv = tid >> 6;
  float acc0 = 0.f, acc1 = 0.f, acc2 = 0.f, acc3 = 0.f;
#pragma unroll
  for (int j = 0; j < 2; ++j) {
    const int d = tid + j * 256;
    const float4 v = *(const float4*)(units + (size_t)d * S_DIM + s0);
    acc0 += v.x * v.x; acc1 += v.y * v.y; acc2 += v.z * v.z; acc3 += v.w * v.w;
    u16 h;
    h = f32_to_bf16(v.x); Uh[(s0 + 0) * DIM + d] = h; Ul[(s0 + 0) * DIM + d] = f32_to_bf16(v.x - bf16_to_f32(h));
    h = f32_to_bf16(v.y); Uh[(s0 + 1) * DIM + d] = h; Ul[(s0 + 1) * DIM + d] = f32_to_bf16(v.y - bf16_to_f32(h));
    h = f32_to_bf16(v.z); Uh[(s0 + 2) * DIM + d] = h; Ul[(s0 + 2) * DIM + d] = f32_to_bf16(v.z - bf16_to_f32(h));
    h = f32_to_bf16(v.w); Uh[(s0 + 3) * DIM + d] = h; Ul[(s0 + 3) * DIM + d] = f32_to_bf16(v.w - bf16_to_f32(h));
  }
#pragma unroll
  for (int off = 1; off < 64; off <<= 1) {
    acc0 += __shfl_xor(acc0, off);
    acc1 += __shfl_xor(acc1, off);
    acc2 += __shfl_xor(acc2, off);
    acc3 += __shfl_xor(acc3, off);
  }
  __shared__ float part[4][4];
  if (lane == 0) { part[wv][0] = acc0; part[wv][1] = acc1; part[wv][2] = acc2; part[wv][3] = acc3; }
  __syncthreads();
  if (tid < 4) msq[s0 + tid] = part[0][tid] + part[1][tid] + part[2][tid] + part[3][tid];
}

// ---------------- K0b: H [b][d][t] -> H^T hi/lo [b][t][d] ----------------
__global__ __launch_bounds__(256) void k_prep_h(const float* __restrict__ H,
                                                u16* __restrict__ Hh, u16* __restrict__ Hl) {
  __shared__ float tile[64 * 68];
  const int t0 = blockIdx.x * 64, d0 = blockIdx.y * 64, b = blockIdx.z;
  const int tid = threadIdx.x;
#pragma unroll
  for (int j = 0; j < 4; ++j) {
    const int chunk = tid + j * 256;
    const int r = chunk >> 4, c4 = (chunk & 15) * 4;
    const float4 v = *(const float4*)(H + ((size_t)(b * DIM + d0 + r)) * T_DIM + t0 + c4);
    *(float4*)(&tile[r * 68 + c4]) = v;
  }
  __syncthreads();
#pragma unroll
  for (int j = 0; j < 2; ++j) {
    const int chunk = tid + j * 256;
    const int q = chunk >> 3, e8 = (chunk & 7) * 8;
    union { u16 us[8]; uint4 v4; } hi, lo;
#pragma unroll
    for (int k = 0; k < 8; ++k) {
      const float f = tile[(e8 + k) * 68 + q];
      const u16 h = f32_to_bf16(f);
      hi.us[k] = h;
      lo.us[k] = f32_to_bf16(f - bf16_to_f32(h));
    }
    const size_t o = ((size_t)(b * T_DIM + t0 + q)) * DIM + d0 + e8;
    *(uint4*)(Hh + o) = hi.v4;
    *(uint4*)(Hl + o) = lo.v4;
  }
}

// ---------------- K1: fused GEMM + softmax ----------------
__device__ __forceinline__ void gl16(const void* g, void* l) {
  __builtin_amdgcn_global_load_lds((const __attribute__((address_space(1))) void*)g,
                                   (__attribute__((address_space(3))) void*)l, 16, 0, 0);
}

#define WAITV(N) asm volatile("s_waitcnt vmcnt(" #N ")" ::: "memory")
#define SYNCPT() do { __builtin_amdgcn_s_barrier(); __builtin_amdgcn_sched_barrier(0); } while (0)
#define LGKM0()  do { asm volatile("s_waitcnt lgkmcnt(0)" ::: "memory"); __builtin_amdgcn_sched_barrier(0); } while (0)

__global__ __launch_bounds__(512, 2) void k_fused(const u16* __restrict__ Uh, const u16* __restrict__ Ul,
                                                  const u16* __restrict__ Hh, const u16* __restrict__ Hl,
                                                  const float* __restrict__ msq,
                                                  float* __restrict__ out) {
  __shared__ __align__(16) char sm[SM_SZ];
  const int tid = threadIdx.x;
  const int lane = tid & 63, wv = tid >> 6;
  const int sw = wv >> 1, tw = wv & 1;          // 4 s-waves x 2 t-waves; wave tile 64s x 32t per chunk
  const int l15 = lane & 15, lhi = lane >> 4;

  const int t00 = blockIdx.x * 64;
  const int bb = blockIdx.y;

  // ---- staging geometry (src-addr XOR swizzle; LDS linear; R3-verified) ----
  // A: 1024 chunks/slab (256 rows x 4), thread does chunks tid, tid+512.
  const int rA0 = tid >> 2;                        // 0..127 (chunk1 row = rA0+128, same swizzle)
  const int csA = ((tid & 3) ^ (rA0 >> 1)) & 3;
  const size_t aBase0 = (size_t)rA0 * 1024 + (size_t)csA * 16;
  const size_t aBase1 = aBase0 + (size_t)128 * 1024;
  // B: 512 chunks/slab (Bh 256 + Bl 256); thread tid does chunk tid.
  const int rB = (tid & 255) >> 2;                 // 0..63
  const int csB = ((tid & 3) ^ (rB >> 1)) & 3;
  const size_t bBase = ((size_t)(bb * T_DIM + t00 + rB)) * 1024 + (size_t)csB * 16;
  const char* const pAh = (const char*)Uh;
  const char* const pAl = (const char*)Ul;
  const char* const pB  = (tid < 256) ? (const char*)Hh : (const char*)Hl;
  const int dT = tid * 16;

#define STAGE(SLOTBASE, J2) do {                                          \
    const size_t aoff = (size_t)((J2) >> 4) * 262144 + (size_t)((J2) & 15) * 64; \
    const size_t boff = (size_t)((J2) & 15) * 64;                         \
    char* d = (SLOTBASE);                                                 \
    gl16(pAh + aBase0 + aoff, d + dT);                                    \
    gl16(pAh + aBase1 + aoff, d + dT + 8192);                             \
    gl16(pAl + aBase0 + aoff, d + A_LO + dT);                             \
    gl16(pAl + aBase1 + aoff, d + A_LO + dT + 8192);                      \
    gl16(pB + bBase + boff, d + B_HI + dT);                               \
  } while (0)

  // ---- fragment read offsets (swizzled chunk idx; lane-const across mt/nt) ----
  const int cidx = ((lhi) ^ (l15 >> 1)) & 3;
  const int offA = sw * 4096 + l15 * 64 + cidx * 16;
  const int offB = tw * 2048 + l15 * 64 + cidx * 16;

  f32x4 acc[4][4][2];
#pragma unroll
  for (int sc = 0; sc < 4; ++sc)
#pragma unroll
    for (int mt = 0; mt < 4; ++mt)
#pragma unroll
      for (int nt = 0; nt < 2; ++nt)
        acc[sc][mt][nt] = (f32x4){0.f, 0.f, 0.f, 0.f};

#define COMPUTE(SC) do {                                                  \
    const char* sl = sm + slotJ * SLOT;                                   \
    short8 ah[4], al[4], bh[2], bl[2];                                    \
    _Pragma("unroll") for (int mt = 0; mt < 4; ++mt) {                    \
      ah[mt] = *(const short8*)(sl + offA + mt * 1024);                   \
      al[mt] = *(const short8*)(sl + A_LO + offA + mt * 1024);            \
    }                                                                     \
    _Pragma("unroll") for (int nt = 0; nt < 2; ++nt) {                    \
      bh[nt] = *(const short8*)(sl + B_HI + offB + nt * 1024);            \
      bl[nt] = *(const short8*)(sl + B_LO + offB + nt * 1024);            \
    }                                                                     \
    LGKM0();                                                              \
    __builtin_amdgcn_s_setprio(1);                                        \
    _Pragma("unroll") for (int mt = 0; mt < 4; ++mt)                      \
      _Pragma("unroll") for (int nt = 0; nt < 2; ++nt) {                  \
        acc[SC][mt][nt] = __builtin_amdgcn_mfma_f32_16x16x32_bf16(ah[mt], bh[nt], acc[SC][mt][nt], 0, 0, 0); \
        acc[SC][mt][nt] = __builtin_amdgcn_mfma_f32_16x16x32_bf16(ah[mt], bl[nt], acc[SC][mt][nt], 0, 0, 0); \
        acc[SC][mt][nt] = __builtin_amdgcn_mfma_f32_16x16x32_bf16(al[mt], bh[nt], acc[SC][mt][nt], 0, 0, 0); \
      }                                                                   \
    __builtin_amdgcn_s_setprio(0);                                        \
  } while (0)

  // ---- prologue: msq -> LDS, stage slabs 0,1 ----
  if (tid < 256) gl16((const char*)msq + tid * 16, sm + MSQ_O + tid * 16);
  STAGE(sm + 0 * SLOT, 0);
  STAGE(sm + 1 * SLOT, 1);

  int slotJ = 0;
#pragma unroll
  for (int sc = 0; sc < 3; ++sc) {
#pragma unroll 1
    for (int k = 0; k < 16; ++k) {
      const int j = sc * 16 + k;
      int slot2 = slotJ + 2; if (slot2 >= 3) slot2 -= 3;
      STAGE(sm + slot2 * SLOT, j + 2);
      WAITV(10); SYNCPT();
      COMPUTE(sc);
      SYNCPT();
      slotJ = (slotJ == 2) ? 0 : slotJ + 1;
    }
  }
#pragma unroll 1
  for (int k = 0; k < 14; ++k) {
    const int j = 48 + k;
    int slot2 = slotJ + 2; if (slot2 >= 3) slot2 -= 3;
    STAGE(sm + slot2 * SLOT, j + 2);
    WAITV(10); SYNCPT();
    COMPUTE(3);
    SYNCPT();
    slotJ = (slotJ == 2) ? 0 : slotJ + 1;
  }
  WAITV(5); SYNCPT(); COMPUTE(3); SYNCPT();
  slotJ = (slotJ == 2) ? 0 : slotJ + 1;
  WAITV(0); SYNCPT(); COMPUTE(3); SYNCPT();

  // ---- epilogue: softmax over s (1024 logits per t, in registers) ----
  // s = sc*256 + sw*64 + mt*16 + lhi*4 + r ; t = t00 + tw*32 + nt*16 + l15
  const float* msql = (const float*)(sm + MSQ_O);
  float* redM = (float*)(sm + REDM_O);
  float* redS = (float*)(sm + REDS_O);

  float m0 = -3.0e38f, m1 = -3.0e38f;
#pragma unroll
  for (int sc = 0; sc < 4; ++sc)
#pragma unroll
    for (int mt = 0; mt < 4; ++mt) {
      const int sb = sc * 256 + sw * 64 + mt * 16 + lhi * 4;
      const f32x4 q = *(const f32x4*)(msql + sb);
#pragma unroll
      for (int r = 0; r < 4; ++r) {
        const float v0 = 2.f * acc[sc][mt][0][r] - q[r];
        const float v1 = 2.f * acc[sc][mt][1][r] - q[r];
        acc[sc][mt][0][r] = v0; acc[sc][mt][1][r] = v1;
        m0 = fmaxf(m0, v0); m1 = fmaxf(m1, v1);
      }
    }
  m0 = fmaxf(m0, __shfl_xor(m0, 16)); m0 = fmaxf(m0, __shfl_xor(m0, 32));
  m1 = fmaxf(m1, __shfl_xor(m1, 16)); m1 = fmaxf(m1, __shfl_xor(m1, 32));
  if (lane < 16) { redM[wv * 32 + lane] = m0; redM[wv * 32 + 16 + lane] = m1; }
  __syncthreads();
  float M0 = redM[tw * 32 + l15], M1 = redM[tw * 32 + 16 + l15];
#pragma unroll
  for (int w = 1; w < 4; ++w) {
    M0 = fmaxf(M0, redM[(tw + 2 * w) * 32 + l15]);
    M1 = fmaxf(M1, redM[(tw + 2 * w) * 32 + 16 + l15]);
  }
  float s0 = 0.f, s1 = 0.f;
#pragma unroll
  for (int sc = 0; sc < 4; ++sc)
#pragma unroll
    for (int mt = 0; mt < 4; ++mt)
#pragma unroll
      for (int r = 0; r < 4; ++r) {
        const float e0 = __expf(acc[sc][mt][0][r] - M0);
        const float e1 = __expf(acc[sc][mt][1][r] - M1);
        acc[sc][mt][0][r] = e0; acc[sc][mt][1][r] = e1;
        s0 += e0; s1 += e1;
      }
  s0 += __shfl_xor(s0, 16); s0 += __shfl_xor(s0, 32);
  s1 += __shfl_xor(s1, 16); s1 += __shfl_xor(s1, 32);
  if (lane < 16) { redS[wv * 32 + lane] = s0; redS[wv * 32 + 16 + lane] = s1; }
  __syncthreads();
  float S0 = redS[tw * 32 + l15], S1 = redS[tw * 32 + 16 + l15];
#pragma unroll
  for (int w = 1; w < 4; ++w) {
    S0 += redS[(tw + 2 * w) * 32 + l15];
    S1 += redS[(tw + 2 * w) * 32 + 16 + l15];
  }
  const float r0 = 1.0f / S0, r1 = 1.0f / S1;

  float* const outb = out + ((size_t)bb << 21);    // b * 1024 * 2048
  const int tbase = t00 + tw * 32 + l15;
#pragma unroll
  for (int sc = 0; sc < 4; ++sc)
#pragma unroll
    for (int mt = 0; mt < 4; ++mt) {
      const int sb = sc * 256 + sw * 64 + mt * 16 + lhi * 4;
#pragma unroll
      for (int r = 0; r < 4; ++r) {
        outb[(size_t)(sb + r) * T_DIM + tbase]      = acc[sc][mt][0][r] * r0;
        outb[(size_t)(sb + r) * T_DIM + tbase + 16] = acc[sc][mt][1][r] * r1;
      }
    }
}

// ---------------- launch ----------------
extern "C" void kernel_launch(void* const* d_in, const int* in_sizes, int n_in,
                              void* d_out, int out_size, void* d_ws, size_t ws_size,
                              hipStream_t stream) {
  (void)in_sizes; (void)n_in; (void)out_size; (void)ws_size;
  const float* H = (const float*)d_in[0];
  const float* units = (const float*)d_in[1];
  float* out = (float*)d_out;
  char* ws = (char*)d_ws;
  u16* Hh = (u16*)(ws);
  u16* Hl = (u16*)(ws + 134217728);
  u16* Uh = (u16*)(ws + 268435456);
  u16* Ul = (u16*)(ws + 269484032);
  float* msq = (float*)(ws + 270532608);

  k_prep_units<<<dim3(S_DIM / 4), 256, 0, stream>>>(units, Uh, Ul, msq);
  k_prep_h<<<dim3(T_DIM / 64, DIM / 64, B_DIM), 256, 0, stream>>>(H, Hh, Hl);
  k_fused<<<dim3(T_DIM / 64, B_DIM), 512, 0, stream>>>(Uh, Ul, Hh, Hl, msq, out);
}